// Round 5
// baseline (11161.130 us; speedup 1.0000x reference)
//
#include <hip/hip_runtime.h>
#include <hip/hip_bf16.h>

#define B   128
#define NA  8
#define AD  16
#define DM  512
#define DI  1024
#define DS  32
#define DC  4
#define DR  32
#define NB  4
#define OD  128

typedef __hip_bfloat16 bf16;

__device__ __forceinline__ float bf2f(bf16 h){ return __bfloat162float(h); }
__device__ __forceinline__ float sigmoidf_(float x){ return 1.0f/(1.0f+__expf(-x)); }
__device__ __forceinline__ float softplusf_(float x){ return fmaxf(x,0.0f)+log1pf(__expf(-fabsf(x))); }

__device__ __forceinline__ float lo2f(unsigned int u){ return __uint_as_float(u<<16); }
__device__ __forceinline__ float hi2f(unsigned int u){ return __uint_as_float(u & 0xffff0000u); }
__device__ __forceinline__ unsigned int packbf2(float a, float b){
    __hip_bfloat16 ha = __float2bfloat16(a), hb = __float2bfloat16(b);
    unsigned short sa = *reinterpret_cast<unsigned short*>(&ha);
    unsigned short sb = *reinterpret_cast<unsigned short*>(&hb);
    return (unsigned int)sa | ((unsigned int)sb << 16);
}

// ---------------- init kernels ----------------

// negA[blk][d][s] = -exp(A_log), blk = b*2+st
__global__ __launch_bounds__(256) void k_negA(const float* __restrict__ Als,
    const float* __restrict__ Alc, float* __restrict__ negA)
{
    int idx = blockIdx.x*256 + threadIdx.x;   // < 2*NB*DI*DS = 262144
    int blk = idx >> 15;
    int r   = idx & 32767;
    int bb = blk >> 1, st = blk & 1;
    const float* src = (st ? Alc : Als) + (size_t)bb*DI*DS + r;
    negA[idx] = -__expf(*src);
}

// x_init[b][m] = b_embed[m] for the chunk
__global__ __launch_bounds__(256) void k_xinit(const float* __restrict__ bemb,
    float* __restrict__ x, int n)
{
    int j = blockIdx.x*256 + threadIdx.x;
    if (j < n) x[j] = bemb[j & (DM-1)];
}

// ctx[i][bl][m] = obs_rep[b0+bl][i][m] + sum_o obs[b0+bl][i][o]*W_obs[o][m]
__global__ __launch_bounds__(256) void k_ctx(const float* __restrict__ obs_rep,
    const float* __restrict__ obs, const float* __restrict__ Wobs,
    float* __restrict__ ctx, int b0, int Bc)
{
    int ib = blockIdx.x;          // < Bc*8
    int bl = ib >> 3, i = ib & 7;
    int ba = b0 + bl;
    __shared__ float orow[OD];
    int tid = threadIdx.x;
    if (tid < OD) orow[tid] = obs[(size_t)(ba*NA+i)*OD + tid];
    __syncthreads();
    for (int m = tid; m < DM; m += 256){
        float acc = obs_rep[(size_t)(ba*NA+i)*DM + m];
        for (int o = 0; o < OD; o++)
            acc += orow[o]*Wobs[o*DM + m];
        ctx[(size_t)(i*Bc + bl)*DM + m] = acc;
    }
}

// ---------------- per-step kernels ----------------

// K1: LN(x)[+ctx] @ W_in -> xz; conv ring (bf16) + silu -> xc; silu(z) -> sz
// grid (32, Bc/16): x = col-tile (64 cols), y = row-tile (16 rows)
__global__ __launch_bounds__(256) void k1_inproj(const float* __restrict__ x,
    const float* __restrict__ ctx, const float* __restrict__ lns,
    const float* __restrict__ Win, bf16* __restrict__ convbuf,
    const float* __restrict__ cw, const float* __restrict__ cb,
    float* __restrict__ xc_out, float* __restrict__ sz_out, int step)
{
    __shared__ float uln[16*512];
    __shared__ float red[512];
    __shared__ float mrow[16], rrow[16];
    int tid = threadIdx.x;
    int r0 = blockIdx.y*16;
    for (int idx = tid; idx < 16*512; idx += 256)
        uln[idx] = x[(size_t)(r0 + (idx>>9))*DM + (idx&511)];
    __syncthreads();
    {
        int row = tid >> 4, part = tid & 15;
        const float* rp = &uln[row*512 + part*32];
        float s = 0.f, s2 = 0.f;
        for (int k = 0; k < 32; k++){ float v = rp[k]; s += v; s2 += v*v; }
        red[row*16+part] = s; red[256 + row*16+part] = s2;
    }
    __syncthreads();
    if (tid < 16){
        float s = 0.f, s2 = 0.f;
        for (int p = 0; p < 16; p++){ s += red[tid*16+p]; s2 += red[256+tid*16+p]; }
        float m = s*(1.0f/512.0f);
        float v = s2*(1.0f/512.0f) - m*m;
        mrow[tid] = m; rrow[tid] = rsqrtf(v + 1e-5f);
    }
    __syncthreads();
    for (int idx = tid; idx < 16*512; idx += 256){
        int row = idx >> 9, k = idx & 511;
        float v = (uln[idx] - mrow[row])*rrow[row]*lns[k];
        if (ctx) v += ctx[(size_t)(r0+row)*DM + k];
        uln[idx] = v;
    }
    __syncthreads();
    int col = blockIdx.x*64 + (tid & 63);
    int rg = tid >> 6;
    float acc[4] = {0.f,0.f,0.f,0.f};
    const float* wp = Win + col;
    const float* u0 = &uln[(rg*4+0)*512];
    const float* u1 = u0 + 512;
    const float* u2 = u1 + 512;
    const float* u3 = u2 + 512;
    for (int k = 0; k < 512; k++){
        float w = wp[(size_t)k*(2*DI)];
        acc[0] += u0[k]*w; acc[1] += u1[k]*w;
        acc[2] += u2[k]*w; acc[3] += u3[k]*w;
    }
    int slot_w = step & 3;
    if (col < DI){
        int d = col;
        float cw0 = cw[0*DI+d], cw1 = cw[1*DI+d];
        float cw2 = cw[2*DI+d], cw3 = cw[3*DI+d];
        float cbd = cb[d];
        for (int rr = 0; rr < 4; rr++){
            int b = r0 + rg*4 + rr;
            float v = acc[rr];
            bf16* bb = convbuf + (size_t)(b*DC)*DI + d;
            bb[(size_t)slot_w*DI] = __float2bfloat16(v);
            float sum = cbd + cw3*v;
            if (step-3 >= 0) sum += cw0*bf2f(bb[(size_t)((step-3)&3)*DI]);
            if (step-2 >= 0) sum += cw1*bf2f(bb[(size_t)((step-2)&3)*DI]);
            if (step-1 >= 0) sum += cw2*bf2f(bb[(size_t)((step-1)&3)*DI]);
            xc_out[(size_t)b*DI + d] = sum*sigmoidf_(sum);
        }
    } else {
        int d = col - DI;
        for (int rr = 0; rr < 4; rr++){
            int b = r0 + rg*4 + rr;
            float v = acc[rr];
            sz_out[(size_t)b*DI + d] = v*sigmoidf_(v);
        }
    }
}

// K2: dbc partials = xc @ W_x, split-K over 4 slices of 256
// grid (4, Bc/32)
__global__ __launch_bounds__(256) void k2_xproj(const float* __restrict__ xc,
    const float* __restrict__ Wx, float* __restrict__ dbc_part, int Bc)
{
    __shared__ float xt[32*256];
    int ks = blockIdx.x, r0 = blockIdx.y*32, k0 = ks*256;
    int tid = threadIdx.x;
    for (int idx = tid; idx < 32*256; idx += 256)
        xt[idx] = xc[(size_t)(r0 + (idx>>8))*DI + k0 + (idx&255)];
    __syncthreads();
    if (tid < 192){
        int colj = tid % 96, rg = tid / 96;
        float acc[16];
        for (int r = 0; r < 16; r++) acc[r] = 0.f;
        for (int kk = 0; kk < 256; kk++){
            float w = Wx[(size_t)(k0+kk)*96 + colj];
            #pragma unroll
            for (int r = 0; r < 16; r++) acc[r] += xt[(rg*16+r)*256 + kk]*w;
        }
        for (int r = 0; r < 16; r++)
            dbc_part[(size_t)ks*(Bc*96) + (size_t)(r0 + rg*16 + r)*96 + colj] = acc[r];
    }
}

// K3: reduce dbc partials; delta = softplus(dt@W_dt + b_dt); h update (bf16); yz
// grid (4, Bc)
__global__ __launch_bounds__(256) void k3_state(const float* __restrict__ dbc_part,
    const float* __restrict__ Wdt, const float* __restrict__ dtb,
    const float* __restrict__ negA, const float* __restrict__ Dp,
    const float* __restrict__ xc, const float* __restrict__ sz,
    unsigned int* __restrict__ h, float* __restrict__ yz, int first, int Bc)
{
    __shared__ float row[96];
    int b = blockIdx.y;
    int d = blockIdx.x*256 + threadIdx.x;
    if (threadIdx.x < 96){
        float v = 0.f;
        for (int ks = 0; ks < 4; ks++)
            v += dbc_part[(size_t)ks*(Bc*96) + (size_t)b*96 + threadIdx.x];
        row[threadIdx.x] = v;
    }
    __syncthreads();
    float dp = 0.f;
    for (int r = 0; r < DR; r++)
        dp += row[r]*Wdt[(size_t)r*DI + d];
    dp += dtb[d];
    float delta = softplusf_(dp);
    float xcv = xc[(size_t)b*DI + d];
    float dxc = delta*xcv;
    const float4* nap = reinterpret_cast<const float4*>(negA + (size_t)d*DS);
    uint4* hp = reinterpret_cast<uint4*>(h + (size_t)(b*DI + d)*(DS/2));
    float y = 0.f;
    #pragma unroll
    for (int q = 0; q < 4; q++){
        uint4 hu = first ? make_uint4(0u,0u,0u,0u) : hp[q];
        float4 na0 = nap[2*q], na1 = nap[2*q+1];
        int s0 = 8*q;
        float h0 = lo2f(hu.x), h1 = hi2f(hu.x);
        float h2 = lo2f(hu.y), h3 = hi2f(hu.y);
        float h4 = lo2f(hu.z), h5 = hi2f(hu.z);
        float h6 = lo2f(hu.w), h7 = hi2f(hu.w);
        h0 = __expf(delta*na0.x)*h0 + dxc*row[DR+s0+0];
        h1 = __expf(delta*na0.y)*h1 + dxc*row[DR+s0+1];
        h2 = __expf(delta*na0.z)*h2 + dxc*row[DR+s0+2];
        h3 = __expf(delta*na0.w)*h3 + dxc*row[DR+s0+3];
        h4 = __expf(delta*na1.x)*h4 + dxc*row[DR+s0+4];
        h5 = __expf(delta*na1.y)*h5 + dxc*row[DR+s0+5];
        h6 = __expf(delta*na1.z)*h6 + dxc*row[DR+s0+6];
        h7 = __expf(delta*na1.w)*h7 + dxc*row[DR+s0+7];
        y += h0*row[DR+DS+s0+0] + h1*row[DR+DS+s0+1]
           + h2*row[DR+DS+s0+2] + h3*row[DR+DS+s0+3]
           + h4*row[DR+DS+s0+4] + h5*row[DR+DS+s0+5]
           + h6*row[DR+DS+s0+6] + h7*row[DR+DS+s0+7];
        hu.x = packbf2(h0,h1); hu.y = packbf2(h2,h3);
        hu.z = packbf2(h4,h5); hu.w = packbf2(h6,h7);
        hp[q] = hu;
    }
    y += Dp[d]*xcv;
    yz[(size_t)b*DI + d] = y*sz[(size_t)b*DI + d];
}

// K4: x += yz @ W_out   grid (8, Bc/32)
__global__ __launch_bounds__(256) void k4_outproj(const float* __restrict__ yz,
    const float* __restrict__ Wout, float* __restrict__ x)
{
    __shared__ float yt[32*256];
    int c0 = blockIdx.x*64, r0 = blockIdx.y*32;
    int tid = threadIdx.x;
    int col = c0 + (tid & 63);
    int rg = tid >> 6;
    float acc[8];
    for (int r = 0; r < 8; r++) acc[r] = 0.f;
    for (int ch = 0; ch < 4; ch++){
        __syncthreads();
        for (int idx = tid; idx < 32*256; idx += 256)
            yt[idx] = yz[(size_t)(r0 + (idx>>8))*DI + ch*256 + (idx&255)];
        __syncthreads();
        for (int kk = 0; kk < 256; kk++){
            float w = Wout[(size_t)(ch*256+kk)*DM + col];
            #pragma unroll
            for (int rr = 0; rr < 8; rr++) acc[rr] += yt[(rg*8+rr)*256 + kk]*w;
        }
    }
    for (int rr = 0; rr < 8; rr++){
        int b = r0 + rg*8 + rr;
        x[(size_t)b*DM + col] += acc[rr];
    }
}

// Head: LN(x)@W_head -> raw/act/lp outputs (FP32 out); next x = act@W_embed + b_embed
// grid (Bc), 128 threads
__global__ __launch_bounds__(128) void k_head(float* __restrict__ x,
    const float* __restrict__ lno, const float* __restrict__ Whead,
    const float* __restrict__ logstd, const float* __restrict__ eps,
    const float* __restrict__ Wemb, const float* __restrict__ bemb,
    float* __restrict__ out, int agent, int b0)
{
    __shared__ float uln[DM];
    __shared__ float red[256];
    __shared__ float actv[AD];
    __shared__ float lpterm[AD];
    __shared__ float ms[2];
    int bl = blockIdx.x, tid = threadIdx.x;
    int ba = b0 + bl;
    float s = 0.f, s2 = 0.f;
    for (int k = tid; k < DM; k += 128){
        float v = x[(size_t)bl*DM + k];
        uln[k] = v; s += v; s2 += v*v;
    }
    red[tid] = s; red[128+tid] = s2;
    __syncthreads();
    if (tid < 32){
        float a = 0.f, a2 = 0.f;
        for (int p = tid; p < 128; p += 32){ a += red[p]; a2 += red[128+p]; }
        red[tid] = a; red[128+tid] = a2;
    }
    __syncthreads();
    if (tid == 0){
        float a = 0.f, a2 = 0.f;
        for (int p = 0; p < 32; p++){ a += red[p]; a2 += red[128+p]; }
        float m = a*(1.0f/DM);
        float v = a2*(1.0f/DM) - m*m;
        ms[0] = m; ms[1] = rsqrtf(v + 1e-5f);
    }
    __syncthreads();
    float m = ms[0], rs = ms[1];
    for (int k = tid; k < DM; k += 128)
        uln[k] = (uln[k]-m)*rs*lno[k];
    __syncthreads();
    if (tid < AD){
        int j = tid;
        float mean = 0.f;
        for (int k = 0; k < DM; k++)
            mean += uln[k]*Whead[k*AD + j];
        float stdj = softplusf_(logstd[j]);
        float e = eps[(size_t)(ba*NA+agent)*AD + j];
        float raw = mean + stdj*e;
        float act = tanhf(raw);
        out[(size_t)(ba*NA+agent)*AD + j] = act;                       // acts
        out[(size_t)NA*B*AD + (size_t)B*NA + (size_t)(ba*NA+agent)*AD + j] = raw;  // raws
        actv[j] = act;
        lpterm[j] = -0.5f*e*e - logf(stdj)
                    - 2.0f*(0.69314718f - raw - softplusf_(-2.0f*raw));
    }
    __syncthreads();
    if (tid == 0){
        float lp = 0.f;
        for (int j = 0; j < AD; j++) lp += lpterm[j];
        lp -= 0.5f*AD*1.8378770664f;
        out[(size_t)NA*B*AD + (size_t)(ba*NA+agent)] = lp;             // logs
    }
    for (int mm = tid; mm < DM; mm += 128){
        float v = bemb[mm];
        #pragma unroll
        for (int j = 0; j < AD; j++)
            v += actv[j]*Wemb[j*DM + mm];
        x[(size_t)bl*DM + mm] = v;
    }
}

// ---------------- launch ----------------

extern "C" void kernel_launch(void* const* d_in, const int* in_sizes, int n_in,
                              void* d_out, int out_size, void* d_ws, size_t ws_size,
                              hipStream_t stream)
{
    const float* in[29];
    for (int k = 0; k < 29; k++) in[k] = (const float*)d_in[k];

    // footprint(Bc) = 1,048,576 + 622,080*Bc bytes
    int Bc = 8;
    if      (ws_size >= 1048576ull + 622080ull*128 + 4096) Bc = 128;
    else if (ws_size >= 1048576ull + 622080ull*64  + 4096) Bc = 64;
    else if (ws_size >= 1048576ull + 622080ull*32  + 4096) Bc = 32;
    else if (ws_size >= 1048576ull + 622080ull*16  + 4096) Bc = 16;
    int nch = B / Bc;

    float* f32 = (float*)d_ws;
    float* negA = f32;                               // 262144 f
    float* ctx  = negA + 262144;                     // 8*Bc*512 = 4096*Bc f
    float* x    = ctx + (size_t)4096*Bc;             // 512*Bc f
    float* xc   = x   + (size_t)512*Bc;              // 1024*Bc f
    float* szb  = xc  + (size_t)1024*Bc;             // 1024*Bc f
    float* yz   = szb + (size_t)1024*Bc;             // 1024*Bc f
    float* dbc  = yz  + (size_t)1024*Bc;             // 4*Bc*96 = 384*Bc f
    unsigned int* h = (unsigned int*)(dbc + (size_t)384*Bc);  // 131072*Bc uints
    bf16* conv = (bf16*)(h + (size_t)131072*Bc);     // 8*Bc*4*1024 bf16

    float* out = (float*)d_out;

    k_negA<<<dim3(1024), 256, 0, stream>>>(in[17], in[26], negA);

    for (int ch = 0; ch < nch; ch++){
        int b0 = ch*Bc;
        k_xinit<<<dim3((Bc*DM+255)/256), 256, 0, stream>>>(in[4], x, Bc*DM);
        k_ctx<<<dim3(Bc*NA), 256, 0, stream>>>(in[0], in[1], in[5], ctx, b0, Bc);

        for (int i = 0; i < NA; i++){
            for (int b = 0; b < NB; b++){
                for (int st = 0; st < 2; st++){
                    int blk = b*2 + st;
                    int base = st ? 20 : 11;
                    const float* Win  = in[base+0] + (size_t)b*DM*2*DI;
                    const float* cw   = in[base+1] + (size_t)b*DC*DI;
                    const float* cb   = in[base+2] + (size_t)b*DI;
                    const float* Wx   = in[base+3] + (size_t)b*DI*96;
                    const float* Wdt  = in[base+4] + (size_t)b*DR*DI;
                    const float* dtb  = in[base+5] + (size_t)b*DI;
                    const float* Dp   = in[base+7] + (size_t)b*DI;
                    const float* Wout = in[base+8] + (size_t)b*DI*DM;
                    const float* lns  = (st ? in[7] : in[6]) + (size_t)b*DM;
                    const float* ctxp = st ? (ctx + (size_t)i*Bc*DM) : nullptr;
                    bf16* convblk = conv + (size_t)blk*Bc*DC*DI;
                    unsigned int* hblk = h + (size_t)blk*Bc*DI*(DS/2);
                    const float* negAblk = negA + (size_t)blk*DI*DS;

                    k1_inproj<<<dim3(32,Bc/16), 256, 0, stream>>>(x, ctxp, lns, Win,
                            convblk, cw, cb, xc, szb, i);
                    k2_xproj<<<dim3(4,Bc/32 > 0 ? Bc/32 : 1), 256, 0, stream>>>(xc, Wx, dbc, Bc);
                    k3_state<<<dim3(4,Bc), 256, 0, stream>>>(dbc, Wdt, dtb, negAblk,
                            Dp, xc, szb, hblk, yz, (i==0) ? 1 : 0, Bc);
                    k4_outproj<<<dim3(8,Bc/32 > 0 ? Bc/32 : 1), 256, 0, stream>>>(yz, Wout, x);
                }
            }
            k_head<<<dim3(Bc), 128, 0, stream>>>(x, in[8], in[9], in[10], in[2],
                    in[3], in[4], out, i, b0);
        }
    }
}

// Round 6
// 7392.613 us; speedup vs baseline: 1.5098x; 1.5098x over previous
//
#include <hip/hip_runtime.h>
#include <hip/hip_bf16.h>

#define B   128
#define NA  8
#define AD  16
#define DM  512
#define DI  1024
#define DS  32
#define DC  4
#define DR  32
#define NB  4
#define OD  128

typedef __hip_bfloat16 bf16;

__device__ __forceinline__ float bf2f(bf16 h){ return __bfloat162float(h); }
__device__ __forceinline__ float sigmoidf_(float x){ return 1.0f/(1.0f+__expf(-x)); }
__device__ __forceinline__ float softplusf_(float x){ return fmaxf(x,0.0f)+log1pf(__expf(-fabsf(x))); }

__device__ __forceinline__ float lo2f(unsigned int u){ return __uint_as_float(u<<16); }
__device__ __forceinline__ float hi2f(unsigned int u){ return __uint_as_float(u & 0xffff0000u); }
__device__ __forceinline__ unsigned int packbf2(float a, float b){
    __hip_bfloat16 ha = __float2bfloat16(a), hb = __float2bfloat16(b);
    unsigned short sa = *reinterpret_cast<unsigned short*>(&ha);
    unsigned short sb = *reinterpret_cast<unsigned short*>(&hb);
    return (unsigned int)sa | ((unsigned int)sb << 16);
}

// ---------------- init kernels ----------------

__global__ __launch_bounds__(256) void k_negA(const float* __restrict__ Als,
    const float* __restrict__ Alc, float* __restrict__ negA)
{
    int idx = blockIdx.x*256 + threadIdx.x;   // < 2*NB*DI*DS = 262144
    int blk = idx >> 15;
    int r   = idx & 32767;
    int bb = blk >> 1, st = blk & 1;
    const float* src = (st ? Alc : Als) + (size_t)bb*DI*DS + r;
    negA[idx] = -__expf(*src);
}

__global__ __launch_bounds__(256) void k_xinit(const float* __restrict__ bemb,
    float* __restrict__ x, int n)
{
    int j = blockIdx.x*256 + threadIdx.x;
    if (j < n) x[j] = bemb[j & (DM-1)];
}

// ctx[i][b][m] = obs_rep[b][i][m] + sum_o obs[b][i][o]*W_obs[o][m]
__global__ __launch_bounds__(256) void k_ctx(const float* __restrict__ obs_rep,
    const float* __restrict__ obs, const float* __restrict__ Wobs,
    float* __restrict__ ctx)
{
    int ib = blockIdx.x;          // < B*8
    int b = ib >> 3, i = ib & 7;
    __shared__ float orow[OD];
    int tid = threadIdx.x;
    if (tid < OD) orow[tid] = obs[(size_t)(b*NA+i)*OD + tid];
    __syncthreads();
    for (int m = tid; m < DM; m += 256){
        float acc = obs_rep[(size_t)(b*NA+i)*DM + m];
        for (int o = 0; o < OD; o++)
            acc += orow[o]*Wobs[o*DM + m];
        ctx[(size_t)(i*B + b)*DM + m] = acc;
    }
}

// ---------------- per-step kernels ----------------

// LN(x)[+ctx] -> uln.  grid(B=128), 256 thr (2 elems/thread)
__global__ __launch_bounds__(256) void k_ln(const float* __restrict__ x,
    const float* __restrict__ ctx, const float* __restrict__ g,
    float* __restrict__ uln)
{
    __shared__ float rs[256], rq[256];
    int b = blockIdx.x, tid = threadIdx.x;
    float v0 = x[(size_t)b*DM + tid];
    float v1 = x[(size_t)b*DM + 256 + tid];
    rs[tid] = v0 + v1;
    rq[tid] = v0*v0 + v1*v1;
    __syncthreads();
    for (int off = 128; off > 0; off >>= 1){
        if (tid < off){ rs[tid] += rs[tid+off]; rq[tid] += rq[tid+off]; }
        __syncthreads();
    }
    float m = rs[0]*(1.0f/DM);
    float var = rq[0]*(1.0f/DM) - m*m;
    float r = rsqrtf(var + 1e-5f);
    float o0 = (v0 - m)*r*g[tid];
    float o1 = (v1 - m)*r*g[256 + tid];
    if (ctx){
        o0 += ctx[(size_t)b*DM + tid];
        o1 += ctx[(size_t)b*DM + 256 + tid];
    }
    uln[(size_t)b*DM + tid] = o0;
    uln[(size_t)b*DM + 256 + tid] = o1;
}

// GEMM1: xz = uln @ W_in  [M=128,N=2048,K=512]; conv ring + silu epilogue.
// grid (8, 32): bx = col-tile (256 cols), by = row-tile (4 rows). 256 thr.
// A-operand reads are wave-uniform -> scalar-cache, no LDS in inner loop.
__global__ __launch_bounds__(256) void k_gemm1(const float* __restrict__ uln,
    const float* __restrict__ Win, bf16* __restrict__ convbuf,
    const float* __restrict__ cw, const float* __restrict__ cb,
    float* __restrict__ xc_out, float* __restrict__ sz_out, int step)
{
    int col = blockIdx.x*256 + threadIdx.x;   // 0..2047
    int r0  = blockIdx.y*4;
    const float* a0 = uln + (size_t)(r0+0)*DM;
    const float* a1 = uln + (size_t)(r0+1)*DM;
    const float* a2 = uln + (size_t)(r0+2)*DM;
    const float* a3 = uln + (size_t)(r0+3)*DM;
    float acc[4] = {0.f,0.f,0.f,0.f};
    #pragma unroll 8
    for (int k = 0; k < DM; k++){
        float w = Win[(size_t)k*(2*DI) + col];
        acc[0] += a0[k]*w; acc[1] += a1[k]*w;
        acc[2] += a2[k]*w; acc[3] += a3[k]*w;
    }
    int slot_w = step & 3;
    if (col < DI){
        int d = col;
        float cw0 = cw[0*DI+d], cw1 = cw[1*DI+d];
        float cw2 = cw[2*DI+d], cw3 = cw[3*DI+d];
        float cbd = cb[d];
        #pragma unroll
        for (int rr = 0; rr < 4; rr++){
            int b = r0 + rr;
            float v = acc[rr];
            bf16* bb = convbuf + (size_t)(b*DC)*DI + d;
            bb[(size_t)slot_w*DI] = __float2bfloat16(v);
            float sum = cbd + cw3*v;
            if (step-3 >= 0) sum += cw0*bf2f(bb[(size_t)((step-3)&3)*DI]);
            if (step-2 >= 0) sum += cw1*bf2f(bb[(size_t)((step-2)&3)*DI]);
            if (step-1 >= 0) sum += cw2*bf2f(bb[(size_t)((step-1)&3)*DI]);
            xc_out[(size_t)b*DI + d] = sum*sigmoidf_(sum);
        }
    } else {
        int d = col - DI;
        #pragma unroll
        for (int rr = 0; rr < 4; rr++){
            int b = r0 + rr;
            float v = acc[rr];
            sz_out[(size_t)b*DI + d] = v*sigmoidf_(v);
        }
    }
}

// dtstate (fused xproj GEMV + dt_proj + h update + y):
// grid (B=128): one block per batch row. 256 thr.
__global__ __launch_bounds__(256) void k_dtstate(const float* __restrict__ xc,
    const float* __restrict__ Wx, const float* __restrict__ Wdt,
    const float* __restrict__ dtb, const float* __restrict__ negA,
    const float* __restrict__ Dp, const float* __restrict__ sz,
    unsigned int* __restrict__ h, float* __restrict__ yz, int first)
{
    __shared__ float part[192];
    __shared__ float row[96];
    int b = blockIdx.x, tid = threadIdx.x;
    const float* xb = xc + (size_t)b*DI;
    // phase A: dbc[96] = xb @ Wx, 2-way split-K (xb reads are wave-uniform)
    if (tid < 192){
        int j  = (tid < 96) ? tid : tid - 96;
        int k0 = (tid < 96) ? 0 : 512;
        float acc = 0.f;
        #pragma unroll 8
        for (int k = 0; k < 512; k++)
            acc += xb[k0+k]*Wx[(size_t)(k0+k)*96 + j];
        part[tid] = acc;
    }
    __syncthreads();
    if (tid < 96) row[tid] = part[tid] + part[tid+96];
    __syncthreads();
    // phase B: per d: delta, h update, y
    for (int q = 0; q < 4; q++){
        int d = q*256 + tid;
        float dp = dtb[d];
        #pragma unroll
        for (int r = 0; r < DR; r++)
            dp += row[r]*Wdt[(size_t)r*DI + d];
        float delta = softplusf_(dp);
        float xcv = xb[d];
        float dxc = delta*xcv;
        const float4* nap = reinterpret_cast<const float4*>(negA + (size_t)d*DS);
        uint4* hp = reinterpret_cast<uint4*>(h + (size_t)(b*DI + d)*(DS/2));
        float y = 0.f;
        #pragma unroll
        for (int qq = 0; qq < 4; qq++){
            uint4 hu = first ? make_uint4(0u,0u,0u,0u) : hp[qq];
            float4 na0 = nap[2*qq], na1 = nap[2*qq+1];
            int s0 = 8*qq;
            float h0 = lo2f(hu.x), h1 = hi2f(hu.x);
            float h2 = lo2f(hu.y), h3 = hi2f(hu.y);
            float h4 = lo2f(hu.z), h5 = hi2f(hu.z);
            float h6 = lo2f(hu.w), h7 = hi2f(hu.w);
            h0 = __expf(delta*na0.x)*h0 + dxc*row[DR+s0+0];
            h1 = __expf(delta*na0.y)*h1 + dxc*row[DR+s0+1];
            h2 = __expf(delta*na0.z)*h2 + dxc*row[DR+s0+2];
            h3 = __expf(delta*na0.w)*h3 + dxc*row[DR+s0+3];
            h4 = __expf(delta*na1.x)*h4 + dxc*row[DR+s0+4];
            h5 = __expf(delta*na1.y)*h5 + dxc*row[DR+s0+5];
            h6 = __expf(delta*na1.z)*h6 + dxc*row[DR+s0+6];
            h7 = __expf(delta*na1.w)*h7 + dxc*row[DR+s0+7];
            y += h0*row[DR+DS+s0+0] + h1*row[DR+DS+s0+1]
               + h2*row[DR+DS+s0+2] + h3*row[DR+DS+s0+3]
               + h4*row[DR+DS+s0+4] + h5*row[DR+DS+s0+5]
               + h6*row[DR+DS+s0+6] + h7*row[DR+DS+s0+7];
            hu.x = packbf2(h0,h1); hu.y = packbf2(h2,h3);
            hu.z = packbf2(h4,h5); hu.w = packbf2(h6,h7);
            hp[qq] = hu;
        }
        y += Dp[d]*xcv;
        yz[(size_t)b*DI + d] = y*sz[(size_t)b*DI + d];
    }
}

// GEMM2: x += yz @ W_out  [M=128,N=512,K=1024]
// grid (4, 64): bx = col-tile (128 cols), by = row-tile (2 rows). 128 thr.
__global__ __launch_bounds__(128) void k_gemm2(const float* __restrict__ yz,
    const float* __restrict__ Wout, float* __restrict__ x)
{
    int col = blockIdx.x*128 + threadIdx.x;   // 0..511
    int r0  = blockIdx.y*2;
    const float* a0 = yz + (size_t)(r0+0)*DI;
    const float* a1 = yz + (size_t)(r0+1)*DI;
    float acc0 = 0.f, acc1 = 0.f;
    #pragma unroll 8
    for (int k = 0; k < DI; k++){
        float w = Wout[(size_t)k*DM + col];
        acc0 += a0[k]*w; acc1 += a1[k]*w;
    }
    x[(size_t)(r0+0)*DM + col] += acc0;
    x[(size_t)(r0+1)*DM + col] += acc1;
}

// Head: LN(x)@W_head -> acts/logs/raws (fp32); next x = act@W_embed + b_embed
// grid (B=128), 128 thr
__global__ __launch_bounds__(128) void k_head(float* __restrict__ x,
    const float* __restrict__ lno, const float* __restrict__ Whead,
    const float* __restrict__ logstd, const float* __restrict__ eps,
    const float* __restrict__ Wemb, const float* __restrict__ bemb,
    float* __restrict__ out, int agent)
{
    __shared__ float uln[DM];
    __shared__ float red[256];
    __shared__ float mpart[128];
    __shared__ float actv[AD];
    __shared__ float lpterm[AD];
    __shared__ float ms[2];
    int b = blockIdx.x, tid = threadIdx.x;
    float s = 0.f, s2 = 0.f;
    for (int k = tid; k < DM; k += 128){
        float v = x[(size_t)b*DM + k];
        uln[k] = v; s += v; s2 += v*v;
    }
    red[tid] = s; red[128+tid] = s2;
    __syncthreads();
    if (tid < 32){
        float a = 0.f, a2 = 0.f;
        for (int p = tid; p < 128; p += 32){ a += red[p]; a2 += red[128+p]; }
        red[tid] = a; red[128+tid] = a2;
    }
    __syncthreads();
    if (tid == 0){
        float a = 0.f, a2 = 0.f;
        for (int p = 0; p < 32; p++){ a += red[p]; a2 += red[128+p]; }
        float m = a*(1.0f/DM);
        float v = a2*(1.0f/DM) - m*m;
        ms[0] = m; ms[1] = rsqrtf(v + 1e-5f);
    }
    __syncthreads();
    float m = ms[0], rs = ms[1];
    for (int k = tid; k < DM; k += 128)
        uln[k] = (uln[k]-m)*rs*lno[k];
    __syncthreads();
    // mean GEMV split over 8 k-groups
    {
        int g = tid >> 4, j = tid & 15;
        float acc = 0.f;
        for (int k = g*64; k < g*64 + 64; k++)
            acc += uln[k]*Whead[k*AD + j];
        mpart[tid] = acc;
    }
    __syncthreads();
    if (tid < AD){
        int j = tid;
        float mean = 0.f;
        #pragma unroll
        for (int g = 0; g < 8; g++) mean += mpart[g*16 + j];
        float stdj = softplusf_(logstd[j]);
        float e = eps[(size_t)(b*NA+agent)*AD + j];
        float raw = mean + stdj*e;
        float act = tanhf(raw);
        out[(size_t)(b*NA+agent)*AD + j] = act;                                      // acts
        out[(size_t)NA*B*AD + (size_t)B*NA + (size_t)(b*NA+agent)*AD + j] = raw;     // raws
        actv[j] = act;
        lpterm[j] = -0.5f*e*e - logf(stdj)
                    - 2.0f*(0.69314718f - raw - softplusf_(-2.0f*raw));
    }
    __syncthreads();
    if (tid == 0){
        float lp = 0.f;
        for (int j = 0; j < AD; j++) lp += lpterm[j];
        lp -= 0.5f*AD*1.8378770664f;
        out[(size_t)NA*B*AD + (size_t)(b*NA+agent)] = lp;                            // logs
    }
    for (int mm = tid; mm < DM; mm += 128){
        float v = bemb[mm];
        #pragma unroll
        for (int j = 0; j < AD; j++)
            v += actv[j]*Wemb[j*DM + mm];
        x[(size_t)b*DM + mm] = v;
    }
}

// ---------------- launch ----------------

extern "C" void kernel_launch(void* const* d_in, const int* in_sizes, int n_in,
                              void* d_out, int out_size, void* d_ws, size_t ws_size,
                              hipStream_t stream)
{
    const float* in[29];
    for (int k = 0; k < 29; k++) in[k] = (const float*)d_in[k];

    // workspace layout (floats) — total ~77.3 MB
    float* f32  = (float*)d_ws;
    float* negA = f32;                               // 262144 f  (1 MB)
    float* ctx  = negA + 262144;                     // 524288 f  (2 MB)
    float* x    = ctx  + 524288;                     // 65536 f
    float* uln  = x    + 65536;                      // 65536 f
    float* xc   = uln  + 65536;                      // 131072 f
    float* szb  = xc   + 131072;                     // 131072 f
    float* yz   = szb  + 131072;                     // 131072 f
    unsigned int* h = (unsigned int*)(yz + 131072);  // 16777216 u (64 MB)
    bf16* conv = (bf16*)(h + 16777216);              // 4194304 bf16 (8 MB)

    float* out = (float*)d_out;

    k_negA<<<dim3(1024), 256, 0, stream>>>(in[17], in[26], negA);
    k_xinit<<<dim3((B*DM+255)/256), 256, 0, stream>>>(in[4], x, B*DM);
    k_ctx<<<dim3(B*NA), 256, 0, stream>>>(in[0], in[1], in[5], ctx);

    for (int i = 0; i < NA; i++){
        for (int b = 0; b < NB; b++){
            for (int st = 0; st < 2; st++){
                int blk = b*2 + st;
                int base = st ? 20 : 11;
                const float* Win  = in[base+0] + (size_t)b*DM*2*DI;
                const float* cw   = in[base+1] + (size_t)b*DC*DI;
                const float* cb   = in[base+2] + (size_t)b*DI;
                const float* Wx   = in[base+3] + (size_t)b*DI*96;
                const float* Wdt  = in[base+4] + (size_t)b*DR*DI;
                const float* dtb  = in[base+5] + (size_t)b*DI;
                const float* Dp   = in[base+7] + (size_t)b*DI;
                const float* Wout = in[base+8] + (size_t)b*DI*DM;
                const float* lns  = (st ? in[7] : in[6]) + (size_t)b*DM;
                const float* ctxp = st ? (ctx + (size_t)i*B*DM) : nullptr;
                bf16* convblk = conv + (size_t)blk*B*DC*DI;
                unsigned int* hblk = h + (size_t)blk*B*DI*(DS/2);
                const float* negAblk = negA + (size_t)blk*DI*DS;

                k_ln<<<dim3(B), 256, 0, stream>>>(x, ctxp, lns, uln);
                k_gemm1<<<dim3(8,32), 256, 0, stream>>>(uln, Win, convblk,
                        cw, cb, xc, szb, i);
                k_dtstate<<<dim3(B), 256, 0, stream>>>(xc, Wx, Wdt, dtb,
                        negAblk, Dp, szb, hblk, yz, (i==0) ? 1 : 0);
                k_gemm2<<<dim3(4,64), 128, 0, stream>>>(yz, Wout, x);
            }
        }
        k_head<<<dim3(B), 128, 0, stream>>>(x, in[8], in[9], in[10], in[2],
                in[3], in[4], out, i);
    }
}